// Round 7
// baseline (10384.730 us; speedup 1.0000x reference)
//
#include <hip/hip_runtime.h>
#include <stdint.h>

#define V_ 16000
#define E_ 512
#define H_ 1024
#define B_ 32
#define T_ 64
#define NG_ 3072        // 3*H rows per weight matrix
#define NR_ 6144        // virtual rows in gru gemm (ih + hh)
#define IHB_ 96         // ih blocks (3072/32)

typedef float f32x4 __attribute__((ext_vector_type(4)));
typedef unsigned long long u64;

__device__ __forceinline__ unsigned int fkey(float f) {
    unsigned int u = __float_as_uint(f);
    return (u & 0x80000000u) ? ~u : (u | 0x80000000u);
}

__device__ __forceinline__ void gload_lds16(const float* g, float* l) {
    __builtin_amdgcn_global_load_lds(
        (const __attribute__((address_space(1))) void*)g,
        (__attribute__((address_space(3))) void*)l, 16, 0, 0);
}

__global__ void init_kernel(const float* __restrict__ hidden,
                            float* __restrict__ h0, float* __restrict__ h1,
                            u64* __restrict__ tokpk) {
    int idx = blockIdx.x * blockDim.x + threadIdx.x;
    if (idx < B_ * H_) {
        h0[idx] = hidden[idx];
        h1[idx] = hidden[B_ * H_ + idx];
    }
    if (idx < T_ * B_) tokpk[idx] = 0ull;
}

// ---------------------------------------------------------------------------
// r4-proven GRU path (gemm_core + ks_reduce + gemm_gru + combine), verbatim.
// ---------------------------------------------------------------------------
__device__ __forceinline__ void gemm_core(
    const float* wp0, const float* wp1,
    const float* ap0, const float* ap1,
    int nch, float* lds, int tid, float acc[4][4])
{
    const int k4s = tid & 15;
    const int r   = tid >> 4;
    const int dW0 = (r << 6) + ((k4s ^ (r & 7)) << 2);
    const int dW1 = dW0 + (16 << 6);
    const int ks   = tid >> 6;
    const int lane = tid & 63;
    const int vg = lane >> 3, bg = lane & 7;

    f32x4 tW0, tW1, tA0, tA1;
    tW0 = *(const f32x4*)(wp0 + (k4s << 2));
    tW1 = *(const f32x4*)(wp1 + (k4s << 2));
    tA0 = *(const f32x4*)(ap0 + (k4s << 2));
    tA1 = *(const f32x4*)(ap1 + (k4s << 2));
    *(f32x4*)&lds[dW0] = tW0;        *(f32x4*)&lds[dW1] = tW1;
    *(f32x4*)&lds[2048 + dW0] = tA0; *(f32x4*)&lds[2048 + dW1] = tA1;
    __syncthreads();

    int cur = 0;
    for (int c = 0; c < nch; c++) {
        if (c + 1 < nch) {
            const int nko = (c + 1) << 6;
            tW0 = *(const f32x4*)(wp0 + nko + (k4s << 2));
            tW1 = *(const f32x4*)(wp1 + nko + (k4s << 2));
            tA0 = *(const f32x4*)(ap0 + nko + (k4s << 2));
            tA1 = *(const f32x4*)(ap1 + nko + (k4s << 2));
        }
        const float* Wb = &lds[cur * 4096];
        const float* Ab = &lds[cur * 4096 + 2048];
        #pragma unroll
        for (int kk = 0; kk < 4; kk++) {
            const int k4 = ks * 4 + kk;
            f32x4 ww[4], ha[4];
            #pragma unroll
            for (int vi = 0; vi < 4; vi++)
                ww[vi] = *(const f32x4*)&Wb[((vg + 8*vi) << 6) + ((k4 ^ vg) << 2)];
            #pragma unroll
            for (int j = 0; j < 4; j++)
                ha[j] = *(const f32x4*)&Ab[((bg + 8*j) << 6) + ((k4 ^ bg) << 2)];
            #pragma unroll
            for (int vi = 0; vi < 4; vi++)
                #pragma unroll
                for (int j = 0; j < 4; j++)
                    acc[vi][j] += ww[vi].x*ha[j].x + ww[vi].y*ha[j].y
                                + ww[vi].z*ha[j].z + ww[vi].w*ha[j].w;
        }
        if (c + 1 < nch) {
            float* Wo = &lds[(cur ^ 1) * 4096];
            *(f32x4*)&Wo[dW0] = tW0;        *(f32x4*)&Wo[dW1] = tW1;
            *(f32x4*)&Wo[2048 + dW0] = tA0; *(f32x4*)&Wo[2048 + dW1] = tA1;
        }
        __syncthreads();
        cur ^= 1;
    }
}

__device__ __forceinline__ void ks_reduce(float* lds, int tid,
                                          float acc[4][4], float tv[16])
{
    const int ks = tid >> 6, lane = tid & 63;
    float* red = lds;                          // [4][64][17]
    float* dst = &red[(ks * 64 + lane) * 17];
    #pragma unroll
    for (int vi = 0; vi < 4; vi++)
        #pragma unroll
        for (int j = 0; j < 4; j++) dst[vi*4 + j] = acc[vi][j];
    __syncthreads();
    if (tid < 64) {
        #pragma unroll
        for (int c = 0; c < 16; c++) {
            float s = 0.f;
            #pragma unroll
            for (int k = 0; k < 4; k++) s += red[(k*64 + tid)*17 + c];
            tv[c] = s;
        }
    }
}

__global__ __launch_bounds__(256) void gemm_gru(
    const float* __restrict__ Wih, const float* __restrict__ Whh, int Kih,
    const float* __restrict__ xbase, int xld,
    const float* __restrict__ embed, const u64* __restrict__ tokprev,
    int t, int tmode,
    const float* __restrict__ hprev,
    float* __restrict__ gbuf)
{
    __shared__ float lds[8192];
    const int tid = threadIdx.x;
    const int blk = blockIdx.x;
    const int r = tid >> 4;

    const float *wp0, *wp1, *ap0, *ap1;
    int nch;
    if (blk < IHB_) {
        const int n0 = blk * 32;
        wp0 = Wih + (size_t)(n0 + r) * Kih;
        wp1 = Wih + (size_t)(n0 + r + 16) * Kih;
        if (tmode) {
            int tok0 = 0, tok1 = 0;
            if (t > 0) {
                tok0 = (int)(0xFFFFFFFFu - (unsigned)(tokprev[r] & 0xFFFFFFFFull));
                tok1 = (int)(0xFFFFFFFFu - (unsigned)(tokprev[r + 16] & 0xFFFFFFFFull));
            }
            ap0 = embed + (size_t)tok0 * Kih;
            ap1 = embed + (size_t)tok1 * Kih;
        } else {
            ap0 = xbase + (size_t)r * xld;
            ap1 = xbase + (size_t)(r + 16) * xld;
        }
        nch = Kih >> 6;
    } else {
        const int n0 = (blk - IHB_) * 32;
        wp0 = Whh + (size_t)(n0 + r) * H_;
        wp1 = Whh + (size_t)(n0 + r + 16) * H_;
        ap0 = hprev + (size_t)r * H_;
        ap1 = hprev + (size_t)(r + 16) * H_;
        nch = H_ >> 6;
    }

    float acc[4][4] = {};
    gemm_core(wp0, wp1, ap0, ap1, nch, lds, tid, acc);
    float tv[16];
    ks_reduce(lds, tid, acc, tv);
    if (tid < 64) {
        const int vgr = tid >> 3, bgr = tid & 7;
        const int nout0 = blk * 32;
        #pragma unroll
        for (int vi = 0; vi < 4; vi++)
            #pragma unroll
            for (int j = 0; j < 4; j++)
                gbuf[(size_t)(bgr + 8*j) * NR_ + nout0 + vgr + 8*vi] = tv[vi*4+j];
    }
}

__global__ __launch_bounds__(256) void combine_kernel(
    const float* __restrict__ gbuf,
    const float* __restrict__ bih, const float* __restrict__ bhh,
    const float* __restrict__ hprev, float* __restrict__ hnew)
{
    const int idx = blockIdx.x * 256 + threadIdx.x;   // 0..32767
    const int b = idx >> 10, i = idx & 1023;
    const float* gb = gbuf + (size_t)b * NR_;
    const float gir = gb[i],        giz = gb[H_ + i],        gin = gb[2*H_ + i];
    const float ghr = gb[NG_ + i],  ghz = gb[NG_ + H_ + i],  ghn = gb[NG_ + 2*H_ + i];
    const float Sr = gir + ghr + bih[i] + bhh[i];
    const float Sz = giz + ghz + bih[H_ + i] + bhh[H_ + i];
    const float rr = 1.f / (1.f + expf(-Sr));
    const float zz = 1.f / (1.f + expf(-Sz));
    const float nn = tanhf(gin + bih[2*H_ + i] + rr * (ghn + bhh[2*H_ + i]));
    const float hp = hprev[(size_t)b * H_ + i];
    hnew[(size_t)b * H_ + i] = (1.f - zz) * nn + zz * hp;
}

// ---------------------------------------------------------------------------
// Logits + fused argmax, DMA-staged W. 16 vocab rows/block (grid 1000).
// W chunk (16 rows x 64 k = 4 KB) double-buffered in LDS via global_load_lds
// (1 instr/wave/chunk, 1 KB each). Pre-swizzled global source (rule #21):
// lane l of wave w fetches k4 = (l&15) ^ (row&7), row = 4w + (l>>4), so the
// linear DMA write lands the XOR layout; compute reads row*64+((k4^row&7)<<2)
// -> 8 distinct bank quads, conflict-free. h1 (A) read per-lane direct from
// global (128 KB, L2-hot; no staging). acc[2][4]: rows vg+8vi, batch bg+8j.
// ---------------------------------------------------------------------------
__global__ __launch_bounds__(256) void logits_kernel(
    const float* __restrict__ h1, const float* __restrict__ Wout,
    const float* __restrict__ bout, float* __restrict__ out_t,
    u64* __restrict__ tokpk_t)
{
    __shared__ float lds[3360];
    const int tid  = threadIdx.x;
    const int lane = tid & 63;
    const int wave = tid >> 6;          // == ks
    const int v0   = blockIdx.x * 16;
    const int vg = lane >> 3, bg = lane & 7;

    // DMA source for this thread's lane slot (constant across chunks)
    const int srow = 4 * wave + (lane >> 4);
    const int sk4  = (lane & 15) ^ (srow & 7);
    const float* gsrc = Wout + (size_t)(v0 + srow) * H_ + sk4 * 4;
    float* ldst0 = &lds[wave * 256];
    float* ldst1 = &lds[1024 + wave * 256];

    const float* ap[4];
    #pragma unroll
    for (int j = 0; j < 4; j++) ap[j] = h1 + (size_t)(bg + 8*j) * H_;

    float acc[2][4] = {};

    // prologue: stage chunk 0 -> buf 0
    gload_lds16(gsrc, ldst0);
    __syncthreads();

    int cur = 0;
    for (int c = 0; c < 16; c++) {
        if (c + 1 < 16)
            gload_lds16(gsrc + (c + 1) * 64, cur ? ldst0 : ldst1);
        const float* Wb = &lds[cur * 1024];
        #pragma unroll
        for (int kk = 0; kk < 4; kk++) {
            const int k4 = wave * 4 + kk;
            f32x4 wv[2], av[4];
            #pragma unroll
            for (int vi = 0; vi < 2; vi++) {
                const int row = vg + 8 * vi;
                wv[vi] = *(const f32x4*)&Wb[(row << 6) + ((k4 ^ (row & 7)) << 2)];
            }
            #pragma unroll
            for (int j = 0; j < 4; j++)
                av[j] = *(const f32x4*)(ap[j] + c * 64 + k4 * 4);
            #pragma unroll
            for (int vi = 0; vi < 2; vi++)
                #pragma unroll
                for (int j = 0; j < 4; j++)
                    acc[vi][j] += wv[vi].x*av[j].x + wv[vi].y*av[j].y
                                + wv[vi].z*av[j].z + wv[vi].w*av[j].w;
        }
        __syncthreads();
        cur ^= 1;
    }

    // ---- reduce across ks, bias, nt-store, argmax (LDS overlay) ----
    {
        float* dst = &lds[(wave * 64 + lane) * 9];
        #pragma unroll
        for (int vi = 0; vi < 2; vi++)
            #pragma unroll
            for (int j = 0; j < 4; j++) dst[vi * 4 + j] = acc[vi][j];
    }
    __syncthreads();
    float* totl = lds + 2304;                       // [32][17]
    u64*   am   = (u64*)(lds + 2848);               // [32][8]
    if (tid < 64) {
        const int vgr = tid >> 3, bgr = tid & 7;
        float tv[2][4];
        #pragma unroll
        for (int vi = 0; vi < 2; vi++) {
            const float bo = bout[v0 + vgr + 8 * vi];
            #pragma unroll
            for (int j = 0; j < 4; j++) {
                float s = 0.f;
                #pragma unroll
                for (int k = 0; k < 4; k++)
                    s += lds[(k * 64 + vgr * 8 + bgr) * 9 + vi * 4 + j];
                tv[vi][j] = s + bo;
            }
        }
        #pragma unroll
        for (int vi = 0; vi < 2; vi++)
            #pragma unroll
            for (int j = 0; j < 4; j++)
                totl[(bgr + 8 * j) * 17 + vgr + 8 * vi] = tv[vi][j];
        #pragma unroll
        for (int j = 0; j < 4; j++) {
            u64 best = 0ull;
            #pragma unroll
            for (int vi = 0; vi < 2; vi++) {
                const int v = v0 + vgr + 8 * vi;
                u64 p = ((u64)fkey(tv[vi][j]) << 32)
                      | (u64)(0xFFFFFFFFu - (unsigned)v);
                best = p > best ? p : best;
            }
            am[(bgr + 8 * j) * 8 + vgr] = best;
        }
    }
    __syncthreads();
    if (tid < 64) {
        const int b = tid >> 1, half = tid & 1;
        #pragma unroll
        for (int q = 0; q < 2; q++) {
            f32x4 o;
            o.x = totl[b * 17 + half * 8 + q * 4 + 0];
            o.y = totl[b * 17 + half * 8 + q * 4 + 1];
            o.z = totl[b * 17 + half * 8 + q * 4 + 2];
            o.w = totl[b * 17 + half * 8 + q * 4 + 3];
            __builtin_nontemporal_store(
                o, (f32x4*)(out_t + (size_t)b * V_ + v0 + half * 8 + q * 4));
        }
    }
    if (tid < 32) {
        u64 best = 0ull;
        #pragma unroll
        for (int q = 0; q < 8; q++) {
            u64 p = am[tid * 8 + q];
            best = p > best ? p : best;
        }
        atomicMax(&tokpk_t[tid], best);
    }
}

extern "C" void kernel_launch(void* const* d_in, const int* in_sizes, int n_in,
                              void* d_out, int out_size, void* d_ws, size_t ws_size,
                              hipStream_t stream) {
    const float* hidden = (const float*)d_in[0];
    const float* embed  = (const float*)d_in[1];
    const float* Wih0   = (const float*)d_in[2];
    const float* Whh0   = (const float*)d_in[3];
    const float* bih0   = (const float*)d_in[4];
    const float* bhh0   = (const float*)d_in[5];
    const float* Wih1   = (const float*)d_in[6];
    const float* Whh1   = (const float*)d_in[7];
    const float* bih1   = (const float*)d_in[8];
    const float* bhh1   = (const float*)d_in[9];
    const float* Wout   = (const float*)d_in[10];
    const float* bout   = (const float*)d_in[11];
    float* out = (float*)d_out;

    const int BH = B_ * H_;
    float* ws = (float*)d_ws;
    float* h0buf = ws;                        // [2][B][H]
    float* h1buf = ws + 2 * BH;               // [2][B][H]
    float* gbuf  = ws + 4 * BH;               // [B][NR_]
    u64* tokpk = (u64*)(ws + 4 * BH + B_ * NR_);  // [T][B]

    init_kernel<<<128, 256, 0, stream>>>(hidden, h0buf, h1buf, tokpk);

    for (int t = 0; t < T_; t++) {
        const int rp = t & 1, wp = (t + 1) & 1;
        const u64* tokprev = tokpk + (size_t)(t > 0 ? t - 1 : 0) * B_;

        gemm_gru<<<NR_ / 32, 256, 0, stream>>>(
            Wih0, Whh0, E_, nullptr, 0, embed, tokprev, t, /*tmode=*/1,
            h0buf + (size_t)rp * BH, gbuf);
        combine_kernel<<<128, 256, 0, stream>>>(
            gbuf, bih0, bhh0, h0buf + (size_t)rp * BH, h0buf + (size_t)wp * BH);

        gemm_gru<<<NR_ / 32, 256, 0, stream>>>(
            Wih1, Whh1, H_, h0buf + (size_t)wp * BH, H_, embed, tokprev, 0,
            /*tmode=*/0, h1buf + (size_t)rp * BH, gbuf);
        combine_kernel<<<128, 256, 0, stream>>>(
            gbuf, bih1, bhh1, h1buf + (size_t)rp * BH, h1buf + (size_t)wp * BH);

        logits_kernel<<<V_ / 16, 256, 0, stream>>>(
            h1buf + (size_t)wp * BH, Wout, bout,
            out + (size_t)t * B_ * V_, tokpk + (size_t)t * B_);
    }
}

// Round 8
// 4334.373 us; speedup vs baseline: 2.3959x; 2.3959x over previous
//
#include <hip/hip_runtime.h>
#include <stdint.h>

#define V_ 16000
#define E_ 512
#define H_ 1024
#define B_ 32
#define T_ 64
#define NG_ 3072        // 3*H rows per weight matrix
#define NR_ 6144        // virtual rows in gru gemm (ih + hh)
#define IHB_ 96         // ih blocks (3072/32)

typedef float f32x4 __attribute__((ext_vector_type(4)));
typedef unsigned long long u64;

__device__ __forceinline__ unsigned int fkey(float f) {
    unsigned int u = __float_as_uint(f);
    return (u & 0x80000000u) ? ~u : (u | 0x80000000u);
}

__global__ void init_kernel(const float* __restrict__ hidden,
                            float* __restrict__ h0, float* __restrict__ h1,
                            u64* __restrict__ tokpk) {
    int idx = blockIdx.x * blockDim.x + threadIdx.x;
    if (idx < B_ * H_) {
        h0[idx] = hidden[idx];
        h1[idx] = hidden[B_ * H_ + idx];
    }
    if (idx < T_ * B_) tokpk[idx] = 0ull;
}

// ---------------------------------------------------------------------------
// Champion gemm_core structure (r5 best = 4374us), widened to 512 threads.
// 32 rows x 32 batch x K tile. Each thread stages 1 W row-chunk + 1 A
// row-chunk (r = tid>>4 in 0..31, k4s = tid&15); 1-chunk-ahead register
// prefetch; XOR-swizzled f32x4 LDS slots (identical layout to champion).
// Compute: ks = tid>>6 in 0..7 (8-way K-split), 2 kk per chunk, acc[4][4]
// (rows vg+8vi, batch bg+8j). 8 waves/block doubles waves/SIMD vs r5.
// ---------------------------------------------------------------------------
__device__ __forceinline__ void gemm_core(
    const float* wp, const float* ap,
    int nch, float* lds, int tid, float acc[4][4])
{
    const int k4s = tid & 15;
    const int r   = tid >> 4;                       // 0..31
    const int dW  = (r << 6) + ((k4s ^ (r & 7)) << 2);
    const int ks   = tid >> 6;                      // 0..7
    const int lane = tid & 63;
    const int vg = lane >> 3, bg = lane & 7;

    f32x4 tW = *(const f32x4*)(wp + (k4s << 2));
    f32x4 tA = *(const f32x4*)(ap + (k4s << 2));
    *(f32x4*)&lds[dW] = tW;
    *(f32x4*)&lds[2048 + dW] = tA;
    __syncthreads();

    int cur = 0;
    for (int c = 0; c < nch; c++) {
        if (c + 1 < nch) {
            const int nko = (c + 1) << 6;
            tW = *(const f32x4*)(wp + nko + (k4s << 2));
            tA = *(const f32x4*)(ap + nko + (k4s << 2));
        }
        const float* Wb = &lds[cur * 4096];
        const float* Ab = &lds[cur * 4096 + 2048];
        #pragma unroll
        for (int kk = 0; kk < 2; kk++) {
            const int k4 = ks * 2 + kk;
            f32x4 ww[4], ha[4];
            #pragma unroll
            for (int vi = 0; vi < 4; vi++)
                ww[vi] = *(const f32x4*)&Wb[((vg + 8*vi) << 6) + ((k4 ^ vg) << 2)];
            #pragma unroll
            for (int j = 0; j < 4; j++)
                ha[j] = *(const f32x4*)&Ab[((bg + 8*j) << 6) + ((k4 ^ bg) << 2)];
            #pragma unroll
            for (int vi = 0; vi < 4; vi++)
                #pragma unroll
                for (int j = 0; j < 4; j++)
                    acc[vi][j] += ww[vi].x*ha[j].x + ww[vi].y*ha[j].y
                                + ww[vi].z*ha[j].z + ww[vi].w*ha[j].w;
        }
        if (c + 1 < nch) {
            float* Wo = &lds[(cur ^ 1) * 4096];
            *(f32x4*)&Wo[dW] = tW;
            *(f32x4*)&Wo[2048 + dW] = tA;
        }
        __syncthreads();
        cur ^= 1;
    }
}

// Sum the 8 ks partials via LDS overlay (free after gemm_core's last barrier).
// On exit tid<64 holds tv[16] for (row vgr+8vi, batch bgr+8j).
__device__ __forceinline__ void ks_reduce(float* lds, int tid,
                                          float acc[4][4], float tv[16])
{
    const int ks = tid >> 6, lane = tid & 63;
    float* dst = &lds[(ks * 64 + lane) * 17];       // [8][64][17]
    #pragma unroll
    for (int vi = 0; vi < 4; vi++)
        #pragma unroll
        for (int j = 0; j < 4; j++) dst[vi*4 + j] = acc[vi][j];
    __syncthreads();
    if (tid < 64) {
        #pragma unroll
        for (int c = 0; c < 16; c++) {
            float s = 0.f;
            #pragma unroll
            for (int k = 0; k < 8; k++) s += lds[(k*64 + tid)*17 + c];
            tv[c] = s;
        }
    }
}

__global__ __launch_bounds__(512) void gemm_gru(
    const float* __restrict__ Wih, const float* __restrict__ Whh, int Kih,
    const float* __restrict__ xbase, int xld,
    const float* __restrict__ embed, const u64* __restrict__ tokprev,
    int t, int tmode,
    const float* __restrict__ hprev,
    float* __restrict__ gbuf)
{
    __shared__ float lds[8704];
    const int tid = threadIdx.x;
    const int blk = blockIdx.x;
    const int r = tid >> 4;                         // 0..31

    const float *wp, *ap;
    int nch;
    if (blk < IHB_) {
        const int n0 = blk * 32;
        wp = Wih + (size_t)(n0 + r) * Kih;
        if (tmode) {
            int tok = 0;
            if (t > 0)
                tok = (int)(0xFFFFFFFFu - (unsigned)(tokprev[r] & 0xFFFFFFFFull));
            ap = embed + (size_t)tok * Kih;
        } else {
            ap = xbase + (size_t)r * xld;
        }
        nch = Kih >> 6;
    } else {
        const int n0 = (blk - IHB_) * 32;
        wp = Whh + (size_t)(n0 + r) * H_;
        ap = hprev + (size_t)r * H_;
        nch = H_ >> 6;
    }

    float acc[4][4] = {};
    gemm_core(wp, ap, nch, lds, tid, acc);
    float tv[16];
    ks_reduce(lds, tid, acc, tv);
    if (tid < 64) {
        const int vgr = tid >> 3, bgr = tid & 7;
        const int nout0 = blk * 32;
        #pragma unroll
        for (int vi = 0; vi < 4; vi++)
            #pragma unroll
            for (int j = 0; j < 4; j++)
                gbuf[(size_t)(bgr + 8*j) * NR_ + nout0 + vgr + 8*vi] = tv[vi*4+j];
    }
}

__global__ __launch_bounds__(256) void combine_kernel(
    const float* __restrict__ gbuf,
    const float* __restrict__ bih, const float* __restrict__ bhh,
    const float* __restrict__ hprev, float* __restrict__ hnew)
{
    const int idx = blockIdx.x * 256 + threadIdx.x;   // 0..32767
    const int b = idx >> 10, i = idx & 1023;
    const float* gb = gbuf + (size_t)b * NR_;
    const float gir = gb[i],        giz = gb[H_ + i],        gin = gb[2*H_ + i];
    const float ghr = gb[NG_ + i],  ghz = gb[NG_ + H_ + i],  ghn = gb[NG_ + 2*H_ + i];
    const float Sr = gir + ghr + bih[i] + bhh[i];
    const float Sz = giz + ghz + bih[H_ + i] + bhh[H_ + i];
    const float rr = 1.f / (1.f + expf(-Sr));
    const float zz = 1.f / (1.f + expf(-Sz));
    const float nn = tanhf(gin + bih[2*H_ + i] + rr * (ghn + bhh[2*H_ + i]));
    const float hp = hprev[(size_t)b * H_ + i];
    hnew[(size_t)b * H_ + i] = (1.f - zz) * nn + zz * hp;
}

// Logits (32 vocab rows/block, grid 500, 512 thr) + bias + nt-store + argmax.
__global__ __launch_bounds__(512) void logits_kernel(
    const float* __restrict__ h1, const float* __restrict__ Wout,
    const float* __restrict__ bout, float* __restrict__ out_t,
    u64* __restrict__ tokpk_t)
{
    __shared__ float lds[10272];   // stream 8192 | red 8704, totl 1056, am 512
    const int tid = threadIdx.x;
    const int r = tid >> 4;                          // 0..31
    const int v0 = blockIdx.x * 32;
    const float* wp = Wout + (size_t)(v0 + r) * H_;
    const float* ap = h1 + (size_t)r * H_;

    float acc[4][4] = {};
    gemm_core(wp, ap, H_ >> 6, lds, tid, acc);
    float tv[16];
    ks_reduce(lds, tid, acc, tv);

    float* totl = lds + 8704;                        // [32][33]
    u64*   am   = (u64*)(lds + 8704 + 1056);         // [32][8]
    if (tid < 64) {
        const int vgr = tid >> 3, bgr = tid & 7;
        #pragma unroll
        for (int vi = 0; vi < 4; vi++) {
            const float bo = bout[v0 + vgr + 8*vi];
            #pragma unroll
            for (int j = 0; j < 4; j++) tv[vi*4+j] += bo;
        }
        #pragma unroll
        for (int vi = 0; vi < 4; vi++)
            #pragma unroll
            for (int j = 0; j < 4; j++)
                totl[(bgr + 8*j) * 33 + vgr + 8*vi] = tv[vi*4+j];
        #pragma unroll
        for (int j = 0; j < 4; j++) {
            u64 best = 0ull;
            #pragma unroll
            for (int vi = 0; vi < 4; vi++) {
                const int v = v0 + vgr + 8*vi;
                u64 p = ((u64)fkey(tv[vi*4+j]) << 32)
                      | (u64)(0xFFFFFFFFu - (unsigned)v);
                best = p > best ? p : best;
            }
            am[(bgr + 8*j) * 8 + vgr] = best;
        }
    }
    __syncthreads();
    if (tid < 64) {
        const int b = tid >> 1, half = tid & 1;
        #pragma unroll
        for (int q = 0; q < 4; q++) {
            f32x4 o;
            o.x = totl[b*33 + half*16 + q*4 + 0];
            o.y = totl[b*33 + half*16 + q*4 + 1];
            o.z = totl[b*33 + half*16 + q*4 + 2];
            o.w = totl[b*33 + half*16 + q*4 + 3];
            __builtin_nontemporal_store(
                o, (f32x4*)(out_t + (size_t)b * V_ + v0 + half*16 + q*4));
        }
    }
    if (tid < 32) {
        u64 best = 0ull;
        #pragma unroll
        for (int q = 0; q < 8; q++) {
            u64 p = am[tid*8 + q];
            best = p > best ? p : best;
        }
        atomicMax(&tokpk_t[tid], best);
    }
}

extern "C" void kernel_launch(void* const* d_in, const int* in_sizes, int n_in,
                              void* d_out, int out_size, void* d_ws, size_t ws_size,
                              hipStream_t stream) {
    const float* hidden = (const float*)d_in[0];
    const float* embed  = (const float*)d_in[1];
    const float* Wih0   = (const float*)d_in[2];
    const float* Whh0   = (const float*)d_in[3];
    const float* bih0   = (const float*)d_in[4];
    const float* bhh0   = (const float*)d_in[5];
    const float* Wih1   = (const float*)d_in[6];
    const float* Whh1   = (const float*)d_in[7];
    const float* bih1   = (const float*)d_in[8];
    const float* bhh1   = (const float*)d_in[9];
    const float* Wout   = (const float*)d_in[10];
    const float* bout   = (const float*)d_in[11];
    float* out = (float*)d_out;

    const int BH = B_ * H_;
    float* ws = (float*)d_ws;
    float* h0buf = ws;                        // [2][B][H]
    float* h1buf = ws + 2 * BH;               // [2][B][H]
    float* gbuf  = ws + 4 * BH;               // [B][NR_]
    u64* tokpk = (u64*)(ws + 4 * BH + B_ * NR_);  // [T][B]

    init_kernel<<<128, 256, 0, stream>>>(hidden, h0buf, h1buf, tokpk);

    for (int t = 0; t < T_; t++) {
        const int rp = t & 1, wp = (t + 1) & 1;
        const u64* tokprev = tokpk + (size_t)(t > 0 ? t - 1 : 0) * B_;

        gemm_gru<<<NR_ / 32, 512, 0, stream>>>(
            Wih0, Whh0, E_, nullptr, 0, embed, tokprev, t, /*tmode=*/1,
            h0buf + (size_t)rp * BH, gbuf);
        combine_kernel<<<128, 256, 0, stream>>>(
            gbuf, bih0, bhh0, h0buf + (size_t)rp * BH, h0buf + (size_t)wp * BH);

        gemm_gru<<<NR_ / 32, 512, 0, stream>>>(
            Wih1, Whh1, H_, h0buf + (size_t)wp * BH, H_, embed, tokprev, 0,
            /*tmode=*/0, h1buf + (size_t)rp * BH, gbuf);
        combine_kernel<<<128, 256, 0, stream>>>(
            gbuf, bih1, bhh1, h1buf + (size_t)rp * BH, h1buf + (size_t)wp * BH);

        logits_kernel<<<V_ / 32, 512, 0, stream>>>(
            h1buf + (size_t)wp * BH, Wout, bout,
            out + (size_t)t * B_ * V_, tokpk + (size_t)t * B_);
    }
}